// Round 21
// baseline (292.629 us; speedup 1.0000x reference)
//
#include <hip/hip_runtime.h>
#include <math.h>

#define LL 512
#define EE 5120
#define RR 160
#define NS 16
#define NTOT 192   // 160 + 16 + 16
#define KS 32      // split-K for g1m
#define KCHUNK 160 // 5120/KS
#define CH 16      // rows per delta tile
#define NCH 8      // chain depth (blocks per e-column)
#define TPC 64     // timesteps per chain block (LL/NCH)
#define SUB 4      // delta tiles per chain block (TPC/CH)
#define ETILES 20  // EE/256

#define XCONV_BLOCKS 1280  // 512*5120 / 2048
#define WALL_TILES   960   // (5120/32)*(192/32)
#define WDT_TILES    800   // (5120/32)*(160/32)

#define LOG2E 1.4426950408889634f

typedef __attribute__((ext_vector_type(8))) short short8;
typedef __attribute__((ext_vector_type(4))) short short4v;
typedef __attribute__((ext_vector_type(4))) float f32x4;
typedef __attribute__((ext_vector_type(2))) float f32x2;

__device__ inline float softplus_t(float z) {
    return z > 20.f ? z : log1pf(__expf(fminf(z, 20.f)));
}

__device__ inline short f2bf(float f) {
    unsigned u = __float_as_uint(f);
    unsigned r = (u + 0x7FFFu + ((u >> 16) & 1u)) >> 16;   // RNE
    return (short)r;
}

__device__ inline float bf2f(unsigned short u) {
    return __uint_as_float(((unsigned)u) << 16);
}

// raw native v_exp_f32 (computes 2^x)
__device__ inline float fexp2(float x) {
    float r;
    asm("v_exp_f32 %0, %1" : "=v"(r) : "v"(x));
    return r;
}

// packed fp32 ops (VOP3P)
__device__ inline f32x2 pk_mul(f32x2 a, f32x2 b) {
    f32x2 r;
    asm("v_pk_mul_f32 %0, %1, %2" : "=v"(r) : "v"(a), "v"(b));
    return r;
}
__device__ inline f32x2 pk_fma(f32x2 a, f32x2 b, f32x2 c) {
    f32x2 r;
    asm("v_pk_fma_f32 %0, %1, %2, %3" : "=v"(r) : "v"(a), "v"(b), "v"(c));
    return r;
}

// ---- prep: x -> xb bf16; weights -> WallT/WdtT bf16; zero chain flags
__global__ __launch_bounds__(256) void prep_kernel(
        const float* __restrict__ x,
        const float* __restrict__ Wlow,
        const float* __restrict__ WB,
        const float* __restrict__ WC,
        const float* __restrict__ Wdt,
        short* __restrict__ xb,
        short* __restrict__ WallT,
        short* __restrict__ WdtT,
        int* __restrict__ flags) {
    const int tid = threadIdx.x;
    const int bid = blockIdx.x;
    if (bid < XCONV_BLOCKS) {
        if (bid == 0 && tid < NCH * ETILES) flags[tid] = 0;
        size_t base = (size_t)bid * 2048 + (size_t)tid * 8;
        float4 v0 = *reinterpret_cast<const float4*>(x + base);
        float4 v1 = *reinterpret_cast<const float4*>(x + base + 4);
        short8 o;
        o[0] = f2bf(v0.x); o[1] = f2bf(v0.y); o[2] = f2bf(v0.z); o[3] = f2bf(v0.w);
        o[4] = f2bf(v1.x); o[5] = f2bf(v1.y); o[6] = f2bf(v1.z); o[7] = f2bf(v1.w);
        *reinterpret_cast<short8*>(xb + base) = o;
        return;
    }
    __shared__ float tile[32][33];
    const int row = tid >> 3, col4 = (tid & 7) * 4;
    if (bid < XCONV_BLOCKS + WALL_TILES) {
        const int t = bid - XCONV_BLOCKS;
        const int k0 = (t / 6) * 32, n0 = (t % 6) * 32;
#pragma unroll
        for (int i = 0; i < 4; ++i) {
            int n = n0 + col4 + i, k = k0 + row;
            float v;
            if (n < RR)            v = Wlow[(size_t)k * RR + n];
            else if (n < RR + NS)  v = WB[(size_t)k * NS + (n - RR)];
            else                   v = WC[(size_t)k * NS + (n - RR - NS)];
            tile[row][col4 + i] = v;
        }
        __syncthreads();
        const int nr = tid >> 3, kc = (tid & 7) * 4;
        short4v o;
#pragma unroll
        for (int i = 0; i < 4; ++i) o[i] = f2bf(tile[kc + i][nr]);
        *reinterpret_cast<short4v*>(WallT + (size_t)(n0 + nr) * EE + k0 + kc) = o;
    } else {
        const int t = bid - XCONV_BLOCKS - WALL_TILES;
        const int n0 = (t / 5) * 32, k0 = (t % 5) * 32;
#pragma unroll
        for (int i = 0; i < 4; ++i)
            tile[row][col4 + i] = Wdt[(size_t)(k0 + row) * EE + n0 + col4 + i];
        __syncthreads();
        const int nr = tid >> 3, kc = (tid & 7) * 4;
        short4v o;
#pragma unroll
        for (int i = 0; i < 4; ++i) o[i] = f2bf(tile[kc + i][nr]);
        *reinterpret_cast<short4v*>(WdtT + (size_t)(n0 + nr) * RR + k0 + kc) = o;
    }
}

// ---- g1m: part[kz][512][192] = xb[:, kz-chunk] @ WallT^T  (bf16 MFMA, bf16 partials)
__global__ __launch_bounds__(256) void g1m_kernel(
        const short* __restrict__ xb,
        const short* __restrict__ WallT,
        short* __restrict__ part) {
    const int tid = threadIdx.x;
    const int w = tid >> 6, l = tid & 63;
    const int wm = w >> 1, wn = w & 1;
    const int m0 = blockIdx.x * 64 + wm * 32;
    const int n0 = blockIdx.y * 64 + wn * 32;
    const int kz = blockIdx.z;
    const int row16 = l & 15, kg = (l >> 4) * 8;
    f32x4 acc[2][2] = {};
    const short* ap0 = xb + (size_t)(m0 + row16) * EE + kz * KCHUNK + kg;
    const short* ap1 = ap0 + (size_t)16 * EE;
    const short* bp0 = WallT + (size_t)(n0 + row16) * EE + kz * KCHUNK + kg;
    const short* bp1 = bp0 + (size_t)16 * EE;
#pragma unroll
    for (int s = 0; s < KCHUNK / 32; ++s) {
        short8 a0 = *reinterpret_cast<const short8*>(ap0 + s * 32);
        short8 a1 = *reinterpret_cast<const short8*>(ap1 + s * 32);
        short8 b0 = *reinterpret_cast<const short8*>(bp0 + s * 32);
        short8 b1 = *reinterpret_cast<const short8*>(bp1 + s * 32);
        acc[0][0] = __builtin_amdgcn_mfma_f32_16x16x32_bf16(a0, b0, acc[0][0], 0, 0, 0);
        acc[0][1] = __builtin_amdgcn_mfma_f32_16x16x32_bf16(a0, b1, acc[0][1], 0, 0, 0);
        acc[1][0] = __builtin_amdgcn_mfma_f32_16x16x32_bf16(a1, b0, acc[1][0], 0, 0, 0);
        acc[1][1] = __builtin_amdgcn_mfma_f32_16x16x32_bf16(a1, b1, acc[1][1], 0, 0, 0);
    }
    const int r0 = (l >> 4) * 4;
    const int c = l & 15;
#pragma unroll
    for (int i = 0; i < 2; ++i)
#pragma unroll
        for (int j = 0; j < 2; ++j) {
            size_t base = ((size_t)kz * LL + (m0 + i * 16 + r0)) * NTOT + (n0 + j * 16 + c);
            part[base]            = f2bf(acc[i][j][0]);
            part[base + NTOT]     = f2bf(acc[i][j][1]);
            part[base + 2 * NTOT] = f2bf(acc[i][j][2]);
            part[base + 3 * NTOT] = f2bf(acc[i][j][3]);
        }
}

// ---- r1: reduce split-K bf16 partials -> tmpb (bf16), Bb, Cb (fp32)
__global__ __launch_bounds__(256) void r1_kernel(
        const short* __restrict__ part,
        short* __restrict__ tmpb,
        float* __restrict__ Bb,
        float* __restrict__ Cb) {
    int idx = blockIdx.x * 256 + threadIdx.x; // 0..98303
    int m = idx / NTOT, j = idx % NTOT;
    float s = 0.f;
#pragma unroll
    for (int ks = 0; ks < KS; ++ks)
        s += bf2f((unsigned short)part[(size_t)ks * LL * NTOT + idx]);
    if (j < RR) tmpb[m * RR + j] = f2bf(s);
    else if (j < RR + NS) Bb[m * NS + (j - RR)] = s;
    else Cb[m * NS + (j - RR - NS)] = s;
}

// Shared helper (R12/R13-verified): delta tile [CH=16 t][256 e] via MFMA into d_lds.
__device__ inline void delta_tile(
        const short* __restrict__ tmpb,
        const short* __restrict__ WdtT,
        const float* __restrict__ bias,
        int t0, int e0, int tid,
        float (*d_lds)[257]) {
    const int w = tid >> 6, l = tid & 63;
    const int row16 = l & 15, koff = (l >> 4) * 8;
    f32x4 acc[4] = {};
    const short* bp = tmpb + (size_t)(t0 + row16) * RR + koff;          // B: t rows
    const short* ap = WdtT + (size_t)(e0 + w * 64 + row16) * RR + koff; // A: e rows
#pragma unroll
    for (int s = 0; s < 5; ++s) {
        short8 b0 = *reinterpret_cast<const short8*>(bp + s * 32);
#pragma unroll
        for (int ef = 0; ef < 4; ++ef) {
            short8 a0 = *reinterpret_cast<const short8*>(ap + (size_t)ef * 16 * RR + s * 32);
            acc[ef] = __builtin_amdgcn_mfma_f32_16x16x32_bf16(a0, b0, acc[ef], 0, 0, 0);
        }
    }
    const int r0 = (l >> 4) * 4, tl = l & 15;
#pragma unroll
    for (int ef = 0; ef < 4; ++ef) {
#pragma unroll
        for (int r = 0; r < 4; ++r) {
            int el = w * 64 + ef * 16 + r0 + r;
            float dv = softplus_t(acc[ef][r] + bias[e0 + el]);
            d_lds[tl][el] = bf2f((unsigned short)f2bf(dv));  // bf16-rounded
        }
    }
}

// ---- scanchain: single-pass scan. Block (c,j) owns timesteps [c*64, c*64+64)
// for e-tile j. Computes delta via MFMA, waits for chunk c-1's h (fp32) via
// flag hand-off, scans 64 steps writing out directly, publishes its h.
__global__ __launch_bounds__(256) void scanchain_kernel(
        const short* __restrict__ tmpb,
        const short* __restrict__ WdtT,
        const float* __restrict__ bias,
        const unsigned short* __restrict__ xb,
        const float* __restrict__ Bb,
        const float* __restrict__ Cb,
        const float* __restrict__ A_log,
        const float* __restrict__ Dvec,
        float* __restrict__ Hinc,
        int* __restrict__ flags,
        float* __restrict__ out) {
    __shared__ float d_lds[CH][257];
    __shared__ unsigned short x_lds[TPC][264];
    __shared__ __align__(16) float b_lds[TPC][NS];
    __shared__ __align__(16) float c_lds[TPC][NS];
    const int bid = blockIdx.x;
    const int c = bid / ETILES, j = bid % ETILES;
    const int e0 = j * 256;
    const int tid = threadIdx.x;
    const int t0g = c * TPC;

    // stage B/C [64][16] and x [64][256]
    for (int v = tid; v < TPC * NS; v += 256) {
        b_lds[v >> 4][v & 15] = Bb[t0g * NS + v];
        c_lds[v >> 4][v & 15] = Cb[t0g * NS + v];
    }
#pragma unroll
    for (int v = tid; v < TPC * 32; v += 256) {
        int ttv = v >> 5, ee = (v & 31) * 8;
        *reinterpret_cast<short8*>(&x_lds[ttv][ee]) =
            *reinterpret_cast<const short8*>(xb + (size_t)(t0g + ttv) * EE + e0 + ee);
    }

    // 4 delta tiles -> per-thread d[64] (static-indexed registers)
    float d[TPC];
#pragma unroll
    for (int s = 0; s < SUB; ++s) {
        delta_tile(tmpb, WdtT, bias, t0g + s * CH, e0, tid, d_lds);
        __syncthreads();
#pragma unroll
        for (int k = 0; k < CH; ++k) d[s * CH + k] = d_lds[k][tid];
        __syncthreads();
    }

    const int e = e0 + tid;
    f32x2 A2[8];
#pragma unroll
    for (int q = 0; q < 4; ++q) {
        float4 al = *reinterpret_cast<const float4*>(&A_log[(size_t)e * NS + q * 4]);
        A2[q * 2 + 0] = (f32x2){-__expf(al.x) * LOG2E, -__expf(al.y) * LOG2E};
        A2[q * 2 + 1] = (f32x2){-__expf(al.z) * LOG2E, -__expf(al.w) * LOG2E};
    }
    const float Dval = Dvec[e];

    // acquire predecessor's h
    f32x2 h2[8];
    if (c == 0) {
#pragma unroll
        for (int i = 0; i < 8; ++i) h2[i] = (f32x2){0.f, 0.f};
    } else {
        if (tid == 0) {
            while (__hip_atomic_load(&flags[bid - ETILES], __ATOMIC_ACQUIRE,
                                     __HIP_MEMORY_SCOPE_AGENT) == 0) {}
        }
        __syncthreads();
        __threadfence();
        const float* hp = Hinc + ((size_t)(c - 1) * EE + e) * NS;
#pragma unroll
        for (int q = 0; q < 4; ++q) {
            float4 hv = *reinterpret_cast<const float4*>(hp + q * 4);
            h2[q * 2 + 0] = (f32x2){hv.x, hv.y};
            h2[q * 2 + 1] = (f32x2){hv.z, hv.w};
        }
    }

    // 64-step scan with direct y/out
#pragma unroll
    for (int tt = 0; tt < TPC; ++tt) {
        float dv = d[tt];
        float xv = bf2f(x_lds[tt][tid]);
        float bx = dv * xv;
        f32x2 d2 = (f32x2){dv, dv};
        f32x2 bx2 = (f32x2){bx, bx};
        float4 b4[4], c4[4];
#pragma unroll
        for (int q = 0; q < 4; ++q) {
            b4[q] = *reinterpret_cast<const float4*>(&b_lds[tt][q * 4]);
            c4[q] = *reinterpret_cast<const float4*>(&c_lds[tt][q * 4]);
        }
        f32x2 y2 = (f32x2){0.f, 0.f};
#pragma unroll
        for (int q = 0; q < 4; ++q) {
            f32x2 blo = (f32x2){b4[q].x, b4[q].y};
            f32x2 bhi = (f32x2){b4[q].z, b4[q].w};
            f32x2 clo = (f32x2){c4[q].x, c4[q].y};
            f32x2 chi = (f32x2){c4[q].z, c4[q].w};
            f32x2 arg0 = pk_mul(d2, A2[q * 2 + 0]);
            f32x2 arg1 = pk_mul(d2, A2[q * 2 + 1]);
            f32x2 a0, a1;
            a0[0] = fexp2(arg0[0]); a0[1] = fexp2(arg0[1]);
            a1[0] = fexp2(arg1[0]); a1[1] = fexp2(arg1[1]);
            f32x2 t0v = pk_mul(bx2, blo);
            f32x2 t1v = pk_mul(bx2, bhi);
            h2[q * 2 + 0] = pk_fma(a0, h2[q * 2 + 0], t0v);
            h2[q * 2 + 1] = pk_fma(a1, h2[q * 2 + 1], t1v);
            y2 = pk_fma(h2[q * 2 + 0], clo, y2);
            y2 = pk_fma(h2[q * 2 + 1], chi, y2);
        }
        out[(size_t)(t0g + tt) * EE + e] = xv * Dval + (y2[0] + y2[1]);
    }

    // publish h (fp32) + flag
    if (c < NCH - 1) {
        float* hp = Hinc + ((size_t)c * EE + e) * NS;
#pragma unroll
        for (int q = 0; q < 4; ++q) {
            float4 hv = {h2[q * 2 + 0][0], h2[q * 2 + 0][1],
                         h2[q * 2 + 1][0], h2[q * 2 + 1][1]};
            *reinterpret_cast<float4*>(hp + q * 4) = hv;
        }
        __threadfence();
        __syncthreads();
        if (tid == 0)
            __hip_atomic_store(&flags[bid], 1, __ATOMIC_RELEASE,
                               __HIP_MEMORY_SCOPE_AGENT);
    }
}

extern "C" void kernel_launch(void* const* d_in, const int* in_sizes, int n_in,
                              void* d_out, int out_size, void* d_ws, size_t ws_size,
                              hipStream_t stream) {
    const float* x     = (const float*)d_in[0];
    const float* Wlow  = (const float*)d_in[1];
    const float* Wdt   = (const float*)d_in[2];
    const float* bias  = (const float*)d_in[3];
    const float* WB    = (const float*)d_in[4];
    const float* WC    = (const float*)d_in[5];
    const float* Alog  = (const float*)d_in[6];
    const float* Dv    = (const float*)d_in[7];
    float* out = (float*)d_out;
    float* wsf = (float*)d_ws;

    // flat workspace layout (float offsets; all 16B-aligned). Total ~18 MB.
    float*          Bb     = wsf;                              // 8192 f32
    float*          Cb     = wsf + 8192;                       // 8192 f32
    short*          WallT  = (short*)(wsf + 16384);            // 983040 bf16
    short*          WdtT   = (short*)(wsf + 507904);           // 819200 bf16
    short*          tmpb   = (short*)(wsf + 917504);           // 81920 bf16
    short*          xb     = (short*)(wsf + 958464);           // 2621440 bf16
    short*          part   = (short*)(wsf + 2269184);          // 3145728 bf16
    float*          Hinc   = wsf + 3842048;                    // 655360 f32
    int*            flags  = (int*)(wsf + 4497408);            // 160 ints

    prep_kernel<<<dim3(XCONV_BLOCKS + WALL_TILES + WDT_TILES), 256, 0, stream>>>(
        x, Wlow, WB, WC, Wdt, xb, WallT, WdtT, flags);
    g1m_kernel<<<dim3(8, 3, KS), 256, 0, stream>>>(xb, WallT, part);
    r1_kernel<<<dim3(384), 256, 0, stream>>>(part, tmpb, Bb, Cb);
    scanchain_kernel<<<dim3(NCH * ETILES), 256, 0, stream>>>(
        tmpb, WdtT, bias, (const unsigned short*)xb, Bb, Cb, Alog, Dv,
        Hinc, flags, out);
}

// Round 22
// 66.039 us; speedup vs baseline: 4.4311x; 4.4311x over previous
//
#include <hip/hip_runtime.h>
#include <math.h>

#define LL 512
#define EE 5120
#define RR 160
#define NS 16
#define NTOT 192   // 160 + 16 + 16
#define KS 32      // split-K for g1m
#define KCHUNK 160 // 5120/KS
#define CH 16      // timesteps per chunk
#define NC 32      // number of chunks (LL/CH)

#define XCONV_BLOCKS 1280  // 512*5120 / 2048
#define WALL_TILES   960   // (5120/32)*(192/32)
#define WDT_TILES    800   // (5120/32)*(160/32)

#define LOG2E 1.4426950408889634f

typedef __attribute__((ext_vector_type(8))) short short8;
typedef __attribute__((ext_vector_type(4))) short short4v;
typedef __attribute__((ext_vector_type(4))) float f32x4;
typedef __attribute__((ext_vector_type(2))) float f32x2;

__device__ inline float softplus_t(float z) {
    return z > 20.f ? z : log1pf(__expf(fminf(z, 20.f)));
}

__device__ inline short f2bf(float f) {
    unsigned u = __float_as_uint(f);
    unsigned r = (u + 0x7FFFu + ((u >> 16) & 1u)) >> 16;   // RNE
    return (short)r;
}

__device__ inline float bf2f(unsigned short u) {
    return __uint_as_float(((unsigned)u) << 16);
}

// raw native v_exp_f32 (computes 2^x) — no OCML guard path, no hidden log2e mul
__device__ inline float fexp2(float x) {
    float r;
    asm("v_exp_f32 %0, %1" : "=v"(r) : "v"(x));
    return r;
}

// packed fp32 ops (VOP3P): 2 fp32 per instruction
__device__ inline f32x2 pk_mul(f32x2 a, f32x2 b) {
    f32x2 r;
    asm("v_pk_mul_f32 %0, %1, %2" : "=v"(r) : "v"(a), "v"(b));
    return r;
}
__device__ inline f32x2 pk_fma(f32x2 a, f32x2 b, f32x2 c) {
    f32x2 r;
    asm("v_pk_fma_f32 %0, %1, %2, %3" : "=v"(r) : "v"(a), "v"(b), "v"(c));
    return r;
}

// ---- prep: x -> xb bf16; [Wlow|WB|WC] -> WallT[192][5120]; Wdt -> WdtT[5120][160]
__global__ __launch_bounds__(256) void prep_kernel(
        const float* __restrict__ x,
        const float* __restrict__ Wlow,
        const float* __restrict__ WB,
        const float* __restrict__ WC,
        const float* __restrict__ Wdt,
        short* __restrict__ xb,
        short* __restrict__ WallT,
        short* __restrict__ WdtT) {
    const int tid = threadIdx.x;
    const int bid = blockIdx.x;
    if (bid < XCONV_BLOCKS) {
        size_t base = (size_t)bid * 2048 + (size_t)tid * 8;
        float4 v0 = *reinterpret_cast<const float4*>(x + base);
        float4 v1 = *reinterpret_cast<const float4*>(x + base + 4);
        short8 o;
        o[0] = f2bf(v0.x); o[1] = f2bf(v0.y); o[2] = f2bf(v0.z); o[3] = f2bf(v0.w);
        o[4] = f2bf(v1.x); o[5] = f2bf(v1.y); o[6] = f2bf(v1.z); o[7] = f2bf(v1.w);
        *reinterpret_cast<short8*>(xb + base) = o;
        return;
    }
    __shared__ float tile[32][33];
    const int row = tid >> 3, col4 = (tid & 7) * 4;
    if (bid < XCONV_BLOCKS + WALL_TILES) {
        const int t = bid - XCONV_BLOCKS;
        const int k0 = (t / 6) * 32, n0 = (t % 6) * 32;
#pragma unroll
        for (int i = 0; i < 4; ++i) {
            int n = n0 + col4 + i, k = k0 + row;
            float v;
            if (n < RR)            v = Wlow[(size_t)k * RR + n];
            else if (n < RR + NS)  v = WB[(size_t)k * NS + (n - RR)];
            else                   v = WC[(size_t)k * NS + (n - RR - NS)];
            tile[row][col4 + i] = v;
        }
        __syncthreads();
        const int nr = tid >> 3, kc = (tid & 7) * 4;
        short4v o;
#pragma unroll
        for (int i = 0; i < 4; ++i) o[i] = f2bf(tile[kc + i][nr]);
        *reinterpret_cast<short4v*>(WallT + (size_t)(n0 + nr) * EE + k0 + kc) = o;
    } else {
        const int t = bid - XCONV_BLOCKS - WALL_TILES;
        const int n0 = (t / 5) * 32, k0 = (t % 5) * 32;
#pragma unroll
        for (int i = 0; i < 4; ++i)
            tile[row][col4 + i] = Wdt[(size_t)(k0 + row) * EE + n0 + col4 + i];
        __syncthreads();
        const int nr = tid >> 3, kc = (tid & 7) * 4;
        short4v o;
#pragma unroll
        for (int i = 0; i < 4; ++i) o[i] = f2bf(tile[kc + i][nr]);
        *reinterpret_cast<short4v*>(WdtT + (size_t)(n0 + nr) * RR + k0 + kc) = o;
    }
}

// ---- g1m: part[kz][512][192] = xb[:, kz-chunk] @ WallT^T  (bf16 MFMA, bf16 partials)
__global__ __launch_bounds__(256) void g1m_kernel(
        const short* __restrict__ xb,
        const short* __restrict__ WallT,
        short* __restrict__ part) {
    const int tid = threadIdx.x;
    const int w = tid >> 6, l = tid & 63;
    const int wm = w >> 1, wn = w & 1;
    const int m0 = blockIdx.x * 64 + wm * 32;
    const int n0 = blockIdx.y * 64 + wn * 32;
    const int kz = blockIdx.z;
    const int row16 = l & 15, kg = (l >> 4) * 8;
    f32x4 acc[2][2] = {};
    const short* ap0 = xb + (size_t)(m0 + row16) * EE + kz * KCHUNK + kg;
    const short* ap1 = ap0 + (size_t)16 * EE;
    const short* bp0 = WallT + (size_t)(n0 + row16) * EE + kz * KCHUNK + kg;
    const short* bp1 = bp0 + (size_t)16 * EE;
#pragma unroll
    for (int s = 0; s < KCHUNK / 32; ++s) {
        short8 a0 = *reinterpret_cast<const short8*>(ap0 + s * 32);
        short8 a1 = *reinterpret_cast<const short8*>(ap1 + s * 32);
        short8 b0 = *reinterpret_cast<const short8*>(bp0 + s * 32);
        short8 b1 = *reinterpret_cast<const short8*>(bp1 + s * 32);
        acc[0][0] = __builtin_amdgcn_mfma_f32_16x16x32_bf16(a0, b0, acc[0][0], 0, 0, 0);
        acc[0][1] = __builtin_amdgcn_mfma_f32_16x16x32_bf16(a0, b1, acc[0][1], 0, 0, 0);
        acc[1][0] = __builtin_amdgcn_mfma_f32_16x16x32_bf16(a1, b0, acc[1][0], 0, 0, 0);
        acc[1][1] = __builtin_amdgcn_mfma_f32_16x16x32_bf16(a1, b1, acc[1][1], 0, 0, 0);
    }
    const int r0 = (l >> 4) * 4;
    const int c = l & 15;
#pragma unroll
    for (int i = 0; i < 2; ++i)
#pragma unroll
        for (int j = 0; j < 2; ++j) {
            size_t base = ((size_t)kz * LL + (m0 + i * 16 + r0)) * NTOT + (n0 + j * 16 + c);
            part[base]            = f2bf(acc[i][j][0]);
            part[base + NTOT]     = f2bf(acc[i][j][1]);
            part[base + 2 * NTOT] = f2bf(acc[i][j][2]);
            part[base + 3 * NTOT] = f2bf(acc[i][j][3]);
        }
}

// ---- r1: reduce split-K bf16 partials -> tmpb (bf16), Bb, Cb (fp32)
__global__ __launch_bounds__(256) void r1_kernel(
        const short* __restrict__ part,
        short* __restrict__ tmpb,
        float* __restrict__ Bb,
        float* __restrict__ Cb) {
    int idx = blockIdx.x * 256 + threadIdx.x; // 0..98303
    int m = idx / NTOT, j = idx % NTOT;
    float s = 0.f;
#pragma unroll
    for (int ks = 0; ks < KS; ++ks)
        s += bf2f((unsigned short)part[(size_t)ks * LL * NTOT + idx]);
    if (j < RR) tmpb[m * RR + j] = f2bf(s);
    else if (j < RR + NS) Bb[m * NS + (j - RR)] = s;
    else Cb[m * NS + (j - RR - NS)] = s;
}

// Shared helper (R12/R13-verified): delta tile [CH=16 t][256 e] via MFMA into d_lds.
__device__ inline void delta_tile(
        const short* __restrict__ tmpb,
        const short* __restrict__ WdtT,
        const float* __restrict__ bias,
        int t0, int e0, int tid,
        float (*d_lds)[257]) {
    const int w = tid >> 6, l = tid & 63;
    const int row16 = l & 15, koff = (l >> 4) * 8;
    f32x4 acc[4] = {};
    const short* bp = tmpb + (size_t)(t0 + row16) * RR + koff;          // B: t rows
    const short* ap = WdtT + (size_t)(e0 + w * 64 + row16) * RR + koff; // A: e rows
#pragma unroll
    for (int s = 0; s < 5; ++s) {
        short8 b0 = *reinterpret_cast<const short8*>(bp + s * 32);
#pragma unroll
        for (int ef = 0; ef < 4; ++ef) {
            short8 a0 = *reinterpret_cast<const short8*>(ap + (size_t)ef * 16 * RR + s * 32);
            acc[ef] = __builtin_amdgcn_mfma_f32_16x16x32_bf16(a0, b0, acc[ef], 0, 0, 0);
        }
    }
    const int r0 = (l >> 4) * 4, tl = l & 15;
#pragma unroll
    for (int ef = 0; ef < 4; ++ef) {
#pragma unroll
        for (int r = 0; r < 4; ++r) {
            int el = w * 64 + ef * 16 + r0 + r;
            float dv = softplus_t(acc[ef][r] + bias[e0 + el]);
            d_lds[tl][el] = bf2f((unsigned short)f2bf(dv));  // bf16-rounded
        }
    }
}

// ---- passAf: fused delta-GEMM + per-chunk local scan -> deltab, Hloc (bf16), sumd (f32)
// packed fp32 h-updates, raw v_exp_f32.
__global__ __launch_bounds__(256) void passAf_kernel(
        const short* __restrict__ tmpb,
        const short* __restrict__ WdtT,
        const float* __restrict__ bias,
        const unsigned short* __restrict__ xb,
        const float* __restrict__ Bb,
        const float* __restrict__ A_log,
        unsigned short* __restrict__ deltab,
        unsigned short* __restrict__ Hloc,
        float* __restrict__ sumd) {
    __shared__ float d_lds[CH][257];
    __shared__ unsigned short x_lds[CH][264];
    __shared__ __align__(16) float b_lds[CH][NS];
    const int c = blockIdx.y;
    const int e0 = blockIdx.x * 256;
    const int tid = threadIdx.x;
    const int t0 = c * CH;

    b_lds[tid >> 4][tid & 15] = Bb[t0 * NS + tid];   // CH*NS == 256
#pragma unroll
    for (int v = tid; v < CH * 32; v += 256) {
        int ttv = v >> 5, ee = (v & 31) * 8;
        short8 xv8 = *reinterpret_cast<const short8*>(xb + (size_t)(t0 + ttv) * EE + e0 + ee);
        *reinterpret_cast<short8*>(&x_lds[ttv][ee]) = xv8;
    }
    delta_tile(tmpb, WdtT, bias, t0, e0, tid, d_lds);
    __syncthreads();

    const int e = e0 + tid;
    f32x2 A2[8];
#pragma unroll
    for (int q = 0; q < 4; ++q) {
        float4 al = *reinterpret_cast<const float4*>(&A_log[(size_t)e * NS + q * 4]);
        A2[q * 2 + 0] = (f32x2){-__expf(al.x) * LOG2E, -__expf(al.y) * LOG2E};
        A2[q * 2 + 1] = (f32x2){-__expf(al.z) * LOG2E, -__expf(al.w) * LOG2E};
    }
    f32x2 h2[8];
#pragma unroll
    for (int i = 0; i < 8; ++i) h2[i] = (f32x2){0.f, 0.f};
    float sd = 0.f;

#pragma unroll
    for (int tt = 0; tt < CH; ++tt) {
        float d = d_lds[tt][tid];
        deltab[(size_t)(t0 + tt) * EE + e] = (unsigned short)f2bf(d);
        float xv = bf2f(x_lds[tt][tid]);
        sd += d;
        float bx = d * xv;
        f32x2 d2 = (f32x2){d, d};
        f32x2 bx2 = (f32x2){bx, bx};
        float4 b4[4];
#pragma unroll
        for (int q = 0; q < 4; ++q)
            b4[q] = *reinterpret_cast<const float4*>(&b_lds[tt][q * 4]);
#pragma unroll
        for (int q = 0; q < 4; ++q) {
            f32x2 blo = (f32x2){b4[q].x, b4[q].y};
            f32x2 bhi = (f32x2){b4[q].z, b4[q].w};
            f32x2 arg0 = pk_mul(d2, A2[q * 2 + 0]);
            f32x2 arg1 = pk_mul(d2, A2[q * 2 + 1]);
            f32x2 a0, a1;
            a0[0] = fexp2(arg0[0]); a0[1] = fexp2(arg0[1]);
            a1[0] = fexp2(arg1[0]); a1[1] = fexp2(arg1[1]);
            f32x2 t0v = pk_mul(bx2, blo);
            f32x2 t1v = pk_mul(bx2, bhi);
            h2[q * 2 + 0] = pk_fma(a0, h2[q * 2 + 0], t0v);
            h2[q * 2 + 1] = pk_fma(a1, h2[q * 2 + 1], t1v);
        }
    }
    size_t base = ((size_t)c * EE + e) * NS;
    short8 p0, p1;
#pragma unroll
    for (int i = 0; i < 4; ++i) {
        p0[i * 2 + 0] = f2bf(h2[i][0]);
        p0[i * 2 + 1] = f2bf(h2[i][1]);
        p1[i * 2 + 0] = f2bf(h2[i + 4][0]);
        p1[i * 2 + 1] = f2bf(h2[i + 4][1]);
    }
    *reinterpret_cast<short8*>(Hloc + base)     = p0;
    *reinterpret_cast<short8*>(Hloc + base + 8) = p1;
    sumd[(size_t)c * EE + e] = sd;
}

// ---- passB: combine across chunks per (e,n); exclusive Hstart
__global__ __launch_bounds__(256) void passB_kernel(
        const unsigned short* __restrict__ Hloc,
        const float* __restrict__ sumd,
        const float* __restrict__ A_log,
        unsigned short* __restrict__ Hstart) {
    const int wk = blockIdx.x * 256 + threadIdx.x;  // (e,n) flat, < 81920
    const int eB = wk >> 4;
    const float Ac2B = -__expf(A_log[wk]) * LOG2E;
    float hs = 0.f;
#pragma unroll
    for (int cc = 0; cc < NC; ++cc) {
        size_t off = (size_t)cc * EE * NS + wk;
        Hstart[off] = (unsigned short)f2bf(hs);
        hs = fexp2(Ac2B * sumd[(size_t)cc * EE + eB]) * hs + bf2f(Hloc[off]);
    }
}

// ---- passC: chunk re-scan seeded with Hstart (packed fp32, raw v_exp_f32)
__global__ __launch_bounds__(256) void passC_kernel(
        const unsigned short* __restrict__ deltab,
        const unsigned short* __restrict__ xb,
        const float* __restrict__ Bb,
        const float* __restrict__ Cb,
        const float* __restrict__ A_log,
        const float* __restrict__ Dvec,
        const unsigned short* __restrict__ Hstart,
        float* __restrict__ out) {
    __shared__ unsigned short dl_lds[CH][264];
    __shared__ unsigned short x_lds[CH][264];
    __shared__ __align__(16) float b_lds[CH][NS];
    __shared__ __align__(16) float c_lds[CH][NS];
    const int c = blockIdx.y;
    const int e0 = blockIdx.x * 256;
    const int tid = threadIdx.x;
    const int t0 = c * CH;

    b_lds[tid >> 4][tid & 15] = Bb[t0 * NS + tid];
    c_lds[tid >> 4][tid & 15] = Cb[t0 * NS + tid];
#pragma unroll
    for (int v = tid; v < CH * 32; v += 256) {
        int ttv = v >> 5, ee = (v & 31) * 8;
        size_t g = (size_t)(t0 + ttv) * EE + e0 + ee;
        *reinterpret_cast<short8*>(&dl_lds[ttv][ee]) =
            *reinterpret_cast<const short8*>(deltab + g);
        *reinterpret_cast<short8*>(&x_lds[ttv][ee]) =
            *reinterpret_cast<const short8*>(xb + g);
    }
    __syncthreads();

    const int e = e0 + tid;
    f32x2 A2[8];
#pragma unroll
    for (int q = 0; q < 4; ++q) {
        float4 al = *reinterpret_cast<const float4*>(&A_log[(size_t)e * NS + q * 4]);
        A2[q * 2 + 0] = (f32x2){-__expf(al.x) * LOG2E, -__expf(al.y) * LOG2E};
        A2[q * 2 + 1] = (f32x2){-__expf(al.z) * LOG2E, -__expf(al.w) * LOG2E};
    }
    f32x2 h2[8];
    size_t base = ((size_t)c * EE + e) * NS;
    {
        short8 p0 = *reinterpret_cast<const short8*>(Hstart + base);
        short8 p1 = *reinterpret_cast<const short8*>(Hstart + base + 8);
#pragma unroll
        for (int i = 0; i < 4; ++i) {
            h2[i]     = (f32x2){bf2f((unsigned short)p0[i * 2]),
                                bf2f((unsigned short)p0[i * 2 + 1])};
            h2[i + 4] = (f32x2){bf2f((unsigned short)p1[i * 2]),
                                bf2f((unsigned short)p1[i * 2 + 1])};
        }
    }
    const float Dval = Dvec[e];

#pragma unroll
    for (int tt = 0; tt < CH; ++tt) {
        float d  = bf2f(dl_lds[tt][tid]);
        float xv = bf2f(x_lds[tt][tid]);
        float bx = d * xv;
        f32x2 d2 = (f32x2){d, d};
        f32x2 bx2 = (f32x2){bx, bx};
        float4 b4[4], c4[4];
#pragma unroll
        for (int q = 0; q < 4; ++q) {
            b4[q] = *reinterpret_cast<const float4*>(&b_lds[tt][q * 4]);
            c4[q] = *reinterpret_cast<const float4*>(&c_lds[tt][q * 4]);
        }
        f32x2 y2 = (f32x2){0.f, 0.f};
#pragma unroll
        for (int q = 0; q < 4; ++q) {
            f32x2 blo = (f32x2){b4[q].x, b4[q].y};
            f32x2 bhi = (f32x2){b4[q].z, b4[q].w};
            f32x2 clo = (f32x2){c4[q].x, c4[q].y};
            f32x2 chi = (f32x2){c4[q].z, c4[q].w};
            f32x2 arg0 = pk_mul(d2, A2[q * 2 + 0]);
            f32x2 arg1 = pk_mul(d2, A2[q * 2 + 1]);
            f32x2 a0, a1;
            a0[0] = fexp2(arg0[0]); a0[1] = fexp2(arg0[1]);
            a1[0] = fexp2(arg1[0]); a1[1] = fexp2(arg1[1]);
            f32x2 t0v = pk_mul(bx2, blo);
            f32x2 t1v = pk_mul(bx2, bhi);
            h2[q * 2 + 0] = pk_fma(a0, h2[q * 2 + 0], t0v);
            h2[q * 2 + 1] = pk_fma(a1, h2[q * 2 + 1], t1v);
            y2 = pk_fma(h2[q * 2 + 0], clo, y2);
            y2 = pk_fma(h2[q * 2 + 1], chi, y2);
        }
        float y = y2[0] + y2[1];
        out[(size_t)(t0 + tt) * EE + e] = xv * Dval + y;
    }
}

extern "C" void kernel_launch(void* const* d_in, const int* in_sizes, int n_in,
                              void* d_out, int out_size, void* d_ws, size_t ws_size,
                              hipStream_t stream) {
    const float* x     = (const float*)d_in[0];
    const float* Wlow  = (const float*)d_in[1];
    const float* Wdt   = (const float*)d_in[2];
    const float* bias  = (const float*)d_in[3];
    const float* WB    = (const float*)d_in[4];
    const float* WC    = (const float*)d_in[5];
    const float* Alog  = (const float*)d_in[6];
    const float* Dv    = (const float*)d_in[7];
    float* out = (float*)d_out;
    float* wsf = (float*)d_ws;

    // flat workspace layout (float offsets; all 16B-aligned). Total ~31.8 MB.
    float*          Bb     = wsf;                              // 8192 f32
    float*          Cb     = wsf + 8192;                       // 8192 f32
    short*          WallT  = (short*)(wsf + 16384);            // 983040 bf16
    short*          WdtT   = (short*)(wsf + 507904);           // 819200 bf16
    short*          tmpb   = (short*)(wsf + 917504);           // 81920 bf16
    short*          xb     = (short*)(wsf + 958464);           // 2621440 bf16
    short*          part   = (short*)(wsf + 2269184);          // 3145728 bf16
    unsigned short* deltab = (unsigned short*)(wsf + 3842048); // 2621440 bf16
    unsigned short* Hloc   = (unsigned short*)(wsf + 5152768); // 2621440 bf16
    unsigned short* Hstart = (unsigned short*)(wsf + 6463488); // 2621440 bf16
    float*          sumd   = wsf + 7774208;                    // 163840 f32

    prep_kernel<<<dim3(XCONV_BLOCKS + WALL_TILES + WDT_TILES), 256, 0, stream>>>(
        x, Wlow, WB, WC, Wdt, xb, WallT, WdtT);
    g1m_kernel<<<dim3(8, 3, KS), 256, 0, stream>>>(xb, WallT, part);
    r1_kernel<<<dim3(384), 256, 0, stream>>>(part, tmpb, Bb, Cb);
    passAf_kernel<<<dim3(EE / 256, NC), 256, 0, stream>>>(
        tmpb, WdtT, bias, (const unsigned short*)xb, Bb, Alog, deltab, Hloc, sumd);
    passB_kernel<<<dim3((EE * NS) / 256), 256, 0, stream>>>(Hloc, sumd, Alog, Hstart);
    passC_kernel<<<dim3(EE / 256, NC), 256, 0, stream>>>(
        (const unsigned short*)deltab, (const unsigned short*)xb, Bb, Cb, Alog, Dv,
        Hstart, out);
}